// Round 23
// baseline (24.977 us; speedup 1.0000x reference)
//
#include <hip/hip_runtime.h>

// CTC batch cost (Keras ctc_batch_cost), B=256, T=512, C=128, L=64.
// r13 structure byte-identical (best verified: 24.3us) + s_setprio:
// consumer wave runs its serial recurrence at priority 1 (dropping to 0
// only around barriers); producer stays at priority 0. Mechanism: CU-level
// wave arbitration — r13/r21/r22 cross-round data shows two actively
// issuing waves slow each other ~1.5x; prioritizing the latency-critical
// chain should reclaim most of it.
// Math: blank-normalized linear domain, 0.5/step decay folded into ql,
// per-lane pow2 exponent, trigger renorm every 4 steps (wave-vote, rare).

#define B_ 256
#define T_ 512
#define C_ 128
#define L_ 64
#define BLANK_ 127
#define EPSF (1e-7f)
#define CHUNK 32
#define QSTR 36            // ql row stride (dwords); 144B -> b128-aligned
#define LN2F 0.6931471805599453f

#define EXP2(x) __builtin_amdgcn_exp2f(x)   // v_exp_f32 (base-2)
#define LOG2(x) __builtin_amdgcn_logf(x)    // v_log_f32 (base-2)

__device__ __forceinline__ float lse2_2(float a, float b) {
    float m = fmaxf(a, b);
    float d = fminf(a, b) - m;
    return m + LOG2(1.0f + EXP2(d));
}

__device__ __forceinline__ float dppf(float x) {  // lane i <- i-1; lane0 <- 0
    return __int_as_float(__builtin_amdgcn_update_dpp(
        0, __float_as_int(x), 0x138, 0xf, 0xf, false));
}
__device__ __forceinline__ int dppi(int x) {
    return __builtin_amdgcn_update_dpp(0, x, 0x138, 0xf, 0xf, false);
}

__device__ __forceinline__ void stage_chunk(const float* gsrc, float* ldst, int lane) {
#pragma unroll
    for (int i = 0; i < CHUNK / 2; ++i) {
        __builtin_amdgcn_global_load_lds(
            (const __attribute__((address_space(1))) void*)(gsrc + i * 256 + lane * 4),
            (__attribute__((address_space(3))) void*)(ldst + i * 256),
            16, 0, 0);
    }
}

__device__ __forceinline__ void produce_chunk(const float* __restrict__ rk,
        float* __restrict__ qd, int lane, int label, int t0, int tend, float& llg)
{
    const float pbv = rk[(lane & 31) * C_ + BLANK_] + EPSF;
    const float rpb = __builtin_amdgcn_rcpf(pbv) * 0.5f;  // 0.5 = decay
    const int t = t0 + lane;
    const bool lgv = (lane < 32) && (t >= 1) && (t < tend);
    llg += lgv ? LOG2(pbv) : 0.0f;
#pragma unroll
    for (int k = 0; k < 8; ++k) {
        float q[4];
#pragma unroll
        for (int j = 0; j < 4; ++j) {
            const int r = 4 * k + j;
            const float pl = rk[r * C_ + label] + EPSF;
            const float rb = __int_as_float(
                __builtin_amdgcn_readlane(__float_as_int(rpb), r));
            q[j] = pl * rb;                   // 0.5*(pl+eps)/(pb+eps)
        }
        *reinterpret_cast<float4*>(qd + lane * QSTR + 4 * k) =
            make_float4(q[0], q[1], q[2], q[3]);
    }
}

// trigger test + rare renorm block (wave-uniform branch)
template<bool HAS128>
__device__ __forceinline__ void maybe_renorm(float& A0, float& A1, float& A2,
                                             int& e, float& sch, float& kq,
                                             float skipf2) {
    float m2 = fmaxf(A0, A1);
    if (HAS128) m2 = fmaxf(m2, A2);
    const bool out = (m2 > 16777216.0f) ||
                     ((m2 < 5.9604644775390625e-8f) && (m2 > 0.0f));  // 2^+-24
    if (__any(out)) {
        const float mm = (m2 == 0.0f) ? 1.0f : m2;
        const int eb = __float_as_int(mm) >> 23;           // biased exp
        const float s = __int_as_float((254 - eb) << 23);  // exact 2^(127-eb)
        A0 *= s; A1 *= s;
        if (HAS128) A2 *= s;
        e += eb - 127;
        const int ep = dppi(e);
        int d = ep - e;
        d = d < -125 ? -125 : d;
        d = d > 127 ? 127 : d;
        sch = __int_as_float((d + 126) << 23);             // 0.5*2^d
        kq = skipf2 * sch;
    }
}

template<bool HAS128>
__device__ __forceinline__ void step(float& A0, float& A1, float& A2,
                                     float sch, float skipf2, float ql) {
    const float P1 = dppf(A1) * sch;          // 0.5*sc*A1prev
    const float A0o = A0, A1o = A1;
    A0 = fmaf(A0o, 0.5f, P1);                 // 0.5*(A0 + sc*A1p)
    const float t = fmaf(skipf2, P1, A0o);    // A0 + sk*sc*A1p
    A1 = (A1o + t) * ql;                      // ql includes the 0.5
    if (HAS128) A2 = (A2 + A1o) * 0.5f;
}

template<bool HAS128>
__device__ __forceinline__ void consumer(const float (*qlbuf)[64 * QSTR],
        const float* extra, int lane, int label, int lab, int tend, int nmax,
        float* out, int b)
{
    const int lprev = __shfl_up(label, 1);
    const float skipf2 = (lane > 0 && label != lprev) ? 2.0f : 0.0f;

    float A0 = 0.0f, A1 = 0.0f, A2 = 0.0f, sch = 0.5f;
    float kq = skipf2 * 0.5f;
    int e = 0;

    for (int c = 0; c < nmax; ++c) {
        const float* qb = &qlbuf[c & 1][lane * QSTR];
        __builtin_amdgcn_s_setprio(1);         // critical: q-load + recurrence
        float qlv[32];
#pragma unroll
        for (int k = 0; k < 8; ++k) {
            const float4 t4 = *reinterpret_cast<const float4*>(qb + 4 * k);
            qlv[4*k+0] = t4.x; qlv[4*k+1] = t4.y;
            qlv[4*k+2] = t4.z; qlv[4*k+3] = t4.w;
        }
        asm volatile("s_waitcnt lgkmcnt(0)" ::: "memory");
        __builtin_amdgcn_s_barrier();          // release buffer to producer
        __builtin_amdgcn_sched_barrier(0);

        const int rem = tend - c * CHUNK;
        if (c == 0) {
            A0 = (lane == 0) ? extra[1] : 0.0f;   // t=0 init (raw, no decay)
            A1 = (lane == 0) ? extra[0] : 0.0f;
#pragma unroll
            for (int u = 1; u < 32; ++u) {
                step<HAS128>(A0, A1, A2, sch, skipf2, qlv[u]);
                if ((u & 3) == 3)
                    maybe_renorm<HAS128>(A0, A1, A2, e, sch, kq, skipf2);
            }
        } else if (rem >= CHUNK) {
#pragma unroll
            for (int u = 0; u < 32; ++u) {
                step<HAS128>(A0, A1, A2, sch, skipf2, qlv[u]);
                if ((u & 3) == 3)
                    maybe_renorm<HAS128>(A0, A1, A2, e, sch, kq, skipf2);
            }
        } else {
            // GUARDED, fully unrolled: no dynamic q[] index, wave-uniform sel
#pragma unroll
            for (int u = 0; u < 32; ++u) {
                const float A0o = A0, A1o = A1, A2o = A2;
                step<HAS128>(A0, A1, A2, sch, skipf2, qlv[u]);
                const bool v = u < rem;
                A0 = v ? A0 : A0o; A1 = v ? A1 : A1o;
                if (HAS128) A2 = v ? A2 : A2o;
                if ((u & 3) == 3)
                    maybe_renorm<HAS128>(A0, A1, A2, e, sch, kq, skipf2);
            }
        }
        __builtin_amdgcn_s_setprio(0);         // about to wait anyway
    }
    __builtin_amdgcn_s_barrier();              // BF: lg ready
    const float lg = extra[2];
    const float ef = (float)e + lg + (float)(tend - 1);   // decay accounting
    const float l0 = LOG2(A0) + ef;
    const float l1 = LOG2(A1) + ef;
    const float a_prev = __shfl(l1, lab - 1);             // state 2*lab-1
    float a_last;
    if (HAS128) {
        const float l2 = LOG2(A2) + ef;
        a_last = __shfl(l2, 63);                          // state 128
    } else {
        a_last = __shfl(l0, lab);                         // state 2*lab
    }
    if (lane == 0) out[b] = -LN2F * lse2_2(a_last, a_prev);
}

__global__ __launch_bounds__(128) void ctc_fwd_kernel(
    const int* __restrict__ y_true, const float* __restrict__ y_pred,
    const int* __restrict__ input_len, const int* __restrict__ label_len,
    float* __restrict__ out)
{
    __shared__ __align__(16) float raw[2][CHUNK * C_];     // 32 KB
    __shared__ __align__(16) float qlbuf[2][64 * QSTR];    // 18.4 KB
    __shared__ float extra[4];                             // A1init, A0init, lg

    const int b = blockIdx.x;
    const int tid = threadIdx.x;
    const int lane = tid & 63;
    const float* __restrict__ Pg = y_pred + (size_t)b * T_ * C_;
    const int label = y_true[b * L_ + lane];
    const int in_len = input_len[b];
    const int tend = in_len < T_ ? in_len : T_;            // >= 256
    const int nmax = (tend + CHUNK - 1) / CHUNK;           // 8..16

    if (tid >= 64) {
        // ------------------------- producer (wave 1) -------------------------
        float llg = 0.0f;
        stage_chunk(Pg, &raw[0][0], lane);
        stage_chunk(Pg + CHUNK * C_, &raw[1][0], lane);
        asm volatile("s_waitcnt vmcnt(16)" ::: "memory");  // chunk0 raw ready
        produce_chunk(&raw[0][0], &qlbuf[0][0], lane, label, 0, tend, llg);
        if (lane == 0) {
            extra[0] = raw[0][label] + EPSF;               // A1 init (s=1)
            extra[1] = raw[0][BLANK_] + EPSF;              // A0 init (s=0)
        }
        asm volatile("s_waitcnt lgkmcnt(0)" ::: "memory");
        __builtin_amdgcn_s_barrier();                      // B0
        for (int c = 0; c < nmax; ++c) {
            if (c + 2 < nmax)
                stage_chunk(Pg + (size_t)(c + 2) * CHUNK * C_, &raw[c & 1][0], lane);
            if (c + 1 < nmax) {
                if (c + 2 < nmax) asm volatile("s_waitcnt vmcnt(16)" ::: "memory");
                else              asm volatile("s_waitcnt vmcnt(0)" ::: "memory");
                produce_chunk(&raw[(c + 1) & 1][0], &qlbuf[(c + 1) & 1][0],
                              lane, label, (c + 1) * CHUNK, tend, llg);
            }
            asm volatile("s_waitcnt lgkmcnt(0)" ::: "memory");
            __builtin_amdgcn_s_barrier();                  // per-chunk
        }
#pragma unroll
        for (int off = 16; off >= 1; off >>= 1) llg += __shfl_xor(llg, off);
        if (lane == 0) extra[2] = llg;                     // lg
        asm volatile("s_waitcnt lgkmcnt(0)" ::: "memory");
        __builtin_amdgcn_s_barrier();                      // BF
    } else {
        // ------------------------- consumer (wave 0) -------------------------
        const int lab = label_len[b];
        __builtin_amdgcn_s_barrier();                      // B0
        if (lab == L_) consumer<true >(qlbuf, extra, lane, label, lab, tend, nmax, out, b);
        else           consumer<false>(qlbuf, extra, lane, label, lab, tend, nmax, out, b);
    }
}

extern "C" void kernel_launch(void* const* d_in, const int* in_sizes, int n_in,
                              void* d_out, int out_size, void* d_ws, size_t ws_size,
                              hipStream_t stream) {
    const int*   y_true    = (const int*)d_in[0];
    const float* y_pred    = (const float*)d_in[1];
    const int*   input_len = (const int*)d_in[2];
    const int*   label_len = (const int*)d_in[3];
    float* out = (float*)d_out;

    ctc_fwd_kernel<<<B_, 128, 0, stream>>>(y_true, y_pred, input_len, label_len, out);
}